// Round 1
// baseline (580.049 us; speedup 1.0000x reference)
//
#include <hip/hip_runtime.h>
#include <hip/hip_fp16.h>

#define N_NODES 50000
#define EMB 128
#define HID 64
#define NR 16
#define NC 16
#define NE 800000
#define J1 (NR*HID + HID)   /* 1088: 16 relations x 64 outs + 64 root cols */
#define J2 (NR*NC + NC)     /* 272:  16 relations x 16 outs + 16 root cols */

// ---------------- build packed B matrices: B1[128][1088], B2[64][272] -------
__global__ void k_build_B(const float* __restrict__ W1, const float* __restrict__ root1,
                          const float* __restrict__ W2, const float* __restrict__ root2,
                          float* __restrict__ B1, float* __restrict__ B2) {
    int idx = blockIdx.x * 256 + threadIdx.x;
    const int total1 = EMB * J1;   // 139264
    const int total2 = HID * J2;   // 17408
    if (idx < total1) {
        int i = idx / J1, j = idx % J1;
        float v = (j < NR*HID) ? W1[((size_t)(j >> 6) * EMB + i) * HID + (j & 63)]
                               : root1[i * HID + (j - NR*HID)];
        B1[idx] = v;
    } else if (idx < total1 + total2) {
        int t = idx - total1;
        int i = t / J2, j = t % J2;
        float v = (j < NR*NC) ? W2[((size_t)(j >> 4) * HID + i) * NC + (j & 15)]
                              : root2[i * NC + (j - NR*NC)];
        B2[t] = v;
    }
}

// ---------------- per-(node,relation) edge counts (float, exact) ------------
__global__ void k_count(const int* __restrict__ dst, const int* __restrict__ et,
                        float* __restrict__ counts) {
    int e = blockIdx.x * 256 + threadIdx.x;
    if (e < NE) atomicAdd(&counts[(size_t)dst[e] * NR + et[e]], 1.0f);
}

// ---------------- dense transform GEMM: C[N,J] = A[N,K] * B[K,J] ------------
// block: 256 threads; tile: 32 nodes x 1024 cols; 4 cols/thread, 32-node acc.
template<int K, typename OutT>
__global__ __launch_bounds__(256)
void k_gemm(const float* __restrict__ A, const float* __restrict__ B,
            OutT* __restrict__ C, int N, int J) {
    __shared__ float xs[32][K];
    int n0 = blockIdx.x * 32;
    for (int idx = threadIdx.x; idx < 32 * (K / 4); idx += 256) {
        int nn = idx / (K / 4), i4 = idx % (K / 4);
        float4 v = make_float4(0.f, 0.f, 0.f, 0.f);
        if (n0 + nn < N) v = reinterpret_cast<const float4*>(A)[(size_t)(n0 + nn) * (K / 4) + i4];
        reinterpret_cast<float4*>(xs[nn])[i4] = v;
    }
    __syncthreads();

    int jb = blockIdx.y * 1024;
    int j0 = jb + threadIdx.x;
    if (j0 >= J) return;                       // cols monotonic -> nothing to do
    bool a1 = (j0 + 256) < J, a2 = (j0 + 512) < J, a3 = (j0 + 768) < J;

    float acc[32][4];
#pragma unroll
    for (int nn = 0; nn < 32; nn++)
#pragma unroll
        for (int c = 0; c < 4; c++) acc[nn][c] = 0.f;

    for (int i0 = 0; i0 < K; i0 += 4) {
        float w[4][4];
#pragma unroll
        for (int k = 0; k < 4; k++) {
            const float* Brow = B + (size_t)(i0 + k) * J;
            w[0][k] = Brow[j0];
            w[1][k] = a1 ? Brow[j0 + 256] : 0.f;
            w[2][k] = a2 ? Brow[j0 + 512] : 0.f;
            w[3][k] = a3 ? Brow[j0 + 768] : 0.f;
        }
#pragma unroll
        for (int nn = 0; nn < 32; nn++) {
            float4 x4 = reinterpret_cast<const float4*>(xs[nn])[i0 / 4];
#pragma unroll
            for (int c = 0; c < 4; c++) {
                acc[nn][c] = fmaf(x4.x, w[c][0], acc[nn][c]);
                acc[nn][c] = fmaf(x4.y, w[c][1], acc[nn][c]);
                acc[nn][c] = fmaf(x4.z, w[c][2], acc[nn][c]);
                acc[nn][c] = fmaf(x4.w, w[c][3], acc[nn][c]);
            }
        }
    }
#pragma unroll
    for (int nn = 0; nn < 32; nn++) {
        if (n0 + nn < N) {
            size_t row = (size_t)(n0 + nn) * J;
            C[row + j0] = (OutT)acc[nn][0];
            if (a1) C[row + j0 + 256] = (OutT)acc[nn][1];
            if (a2) C[row + j0 + 512] = (OutT)acc[nn][2];
            if (a3) C[row + j0 + 768] = (OutT)acc[nn][3];
        }
    }
}

// ---------------- layer-1 aggregation: wave per edge, 64-wide atomics -------
__global__ void k_agg1(const int* __restrict__ ei, const int* __restrict__ et,
                       const float* __restrict__ counts, const __half* __restrict__ Y1,
                       float* __restrict__ H1) {
    int e = blockIdx.x * 4 + (threadIdx.x >> 6);
    if (e >= NE) return;
    int lane = threadIdx.x & 63;
    int s = ei[e], d = ei[NE + e], t = et[e];
    float c = counts[(size_t)d * NR + t];
    float w = 1.0f / fmaxf(c, 1.0f);
    float v = __half2float(Y1[(size_t)s * J1 + t * HID + lane]);
    atomicAdd(&H1[(size_t)d * HID + lane], v * w);
}

// ---------------- finalize layer 1: relu(H1 + root-term + b1) ---------------
__global__ void k_fin1(const float* __restrict__ H1, const __half* __restrict__ Y1,
                       const float* __restrict__ b1, float* __restrict__ X1) {
    int idx = blockIdx.x * 256 + threadIdx.x;     // n*64 + o
    if (idx >= N_NODES * HID) return;
    int n = idx >> 6, o = idx & 63;
    float v = H1[idx] + __half2float(Y1[(size_t)n * J1 + NR*HID + o]) + b1[o];
    X1[idx] = fmaxf(v, 0.0f);
}

// ---------------- layer-2 aggregation: 16 lanes per edge --------------------
__global__ void k_agg2(const int* __restrict__ ei, const int* __restrict__ et,
                       const float* __restrict__ counts, const float* __restrict__ Y2,
                       float* __restrict__ H2out) {
    int idx = blockIdx.x * 256 + threadIdx.x;
    int e = idx >> 4;
    if (e >= NE) return;
    int o = idx & 15;
    int s = ei[e], d = ei[NE + e], t = et[e];
    float c = counts[(size_t)d * NR + t];
    float w = 1.0f / fmaxf(c, 1.0f);
    float v = Y2[(size_t)s * J2 + t * NC + o];
    atomicAdd(&H2out[(size_t)d * NC + o], v * w);
}

// ---------------- finalize layer 2: sigmoid(H2 + root-term + b2) ------------
__global__ void k_fin2(float* __restrict__ out, const float* __restrict__ Y2,
                       const float* __restrict__ b2) {
    int idx = blockIdx.x * 256 + threadIdx.x;     // n*16 + o
    if (idx >= N_NODES * NC) return;
    int n = idx >> 4, o = idx & 15;
    float v = out[idx] + Y2[(size_t)n * J2 + NR*NC + o] + b2[o];
    out[idx] = 1.0f / (1.0f + expf(-v));
}

extern "C" void kernel_launch(void* const* d_in, const int* in_sizes, int n_in,
                              void* d_out, int out_size, void* d_ws, size_t ws_size,
                              hipStream_t stream) {
    const float* emb   = (const float*)d_in[0];
    const float* W1    = (const float*)d_in[1];
    const float* root1 = (const float*)d_in[2];
    const float* b1    = (const float*)d_in[3];
    const float* W2    = (const float*)d_in[4];
    const float* root2 = (const float*)d_in[5];
    const float* b2    = (const float*)d_in[6];
    const int*   ei    = (const int*)d_in[7];    // [2, NE]: src then dst
    const int*   et    = (const int*)d_in[8];
    float* out = (float*)d_out;

    char* ws = (char*)d_ws;
    // ws layout (bytes):
    //   counts: 0          .. 3,200,000      (800000 f32)
    //   B1:     3,200,000  .. +557,056       (128x1088 f32)
    //   B2:     3,757,056  .. +69,632        (64x272 f32)
    //   H1:     3,826,688  .. +12,800,000    (50000x64 f32)
    //   X1:     16,626,688 .. +12,800,000    (50000x64 f32)
    //   Y:      29,426,688 .. +108,800,000   (Y1 fp16 50000x1088; Y2 f32 50000x272 aliased)
    float*  counts = (float*)(ws + 0);
    float*  B1     = (float*)(ws + 3200000);
    float*  B2     = (float*)(ws + 3757056);
    float*  H1     = (float*)(ws + 3826688);
    float*  X1     = (float*)(ws + 16626688);
    __half* Y1     = (__half*)(ws + 29426688);
    float*  Y2     = (float*)(ws + 29426688);   // reuses Y1 space after fin1

    hipMemsetAsync(counts, 0, 3200000, stream);
    hipMemsetAsync(H1, 0, 12800000, stream);
    hipMemsetAsync(out, 0, (size_t)N_NODES * NC * sizeof(float), stream);

    k_build_B<<<613, 256, 0, stream>>>(W1, root1, W2, root2, B1, B2);
    k_count<<<(NE + 255) / 256, 256, 0, stream>>>(ei + NE, et, counts);

    dim3 g1((N_NODES + 31) / 32, 2);
    k_gemm<EMB, __half><<<g1, 256, 0, stream>>>(emb, B1, Y1, N_NODES, J1);

    k_agg1<<<NE / 4, 256, 0, stream>>>(ei, et, counts, Y1, H1);
    k_fin1<<<(N_NODES * HID + 255) / 256, 256, 0, stream>>>(H1, Y1, b1, X1);

    dim3 g2((N_NODES + 31) / 32, 1);
    k_gemm<HID, float><<<g2, 256, 0, stream>>>(X1, B2, Y2, N_NODES, J2);

    k_agg2<<<(NE * NC) / 256, 256, 0, stream>>>(ei, et, counts, Y2, out);
    k_fin2<<<(N_NODES * NC + 255) / 256, 256, 0, stream>>>(out, Y2, b2);
}

// Round 2
// 357.920 us; speedup vs baseline: 1.6206x; 1.6206x over previous
//
#include <hip/hip_runtime.h>
#include <hip/hip_fp16.h>

#define N_NODES 50000
#define EMB 128
#define HID 64
#define NR 16
#define NC 16
#define NE 800000
#define J1 (NR*HID + HID)   /* 1088 */
#define J2 (NR*NC + NC)     /* 272  */

typedef _Float16 f16;
typedef __attribute__((ext_vector_type(8))) _Float16 f16x8;
typedef __attribute__((ext_vector_type(4))) _Float16 f16x4;
typedef __attribute__((ext_vector_type(4))) float f32x4;

// ---------------- build packed transposed fp16 B: Bt1[1088][128], Bt2[272][64]
__global__ void k_build_B(const float* __restrict__ W1, const float* __restrict__ root1,
                          const float* __restrict__ W2, const float* __restrict__ root2,
                          f16* __restrict__ Bt1, f16* __restrict__ Bt2) {
    int idx = blockIdx.x * 256 + threadIdx.x;
    const int total1 = J1 * EMB;   // 139264
    const int total2 = J2 * HID;   // 17408
    if (idx < total1) {
        int j = idx / EMB, i = idx % EMB;
        float v = (j < NR*HID) ? W1[((size_t)(j >> 6) * EMB + i) * HID + (j & 63)]
                               : root1[i * HID + (j - NR*HID)];
        Bt1[idx] = (f16)v;
    } else if (idx < total1 + total2) {
        int t = idx - total1;
        int j = t / HID, i = t % HID;
        float v = (j < NR*NC) ? W2[((size_t)(j >> 4) * HID + i) * NC + (j & 15)]
                              : root2[i * NC + (j - NR*NC)];
        Bt2[t] = (f16)v;
    }
}

// ---------------- fp32 -> fp16 cast (vectorized) ----------------------------
__global__ void k_cast(const float* __restrict__ x, f16* __restrict__ y, int n4) {
    int i = blockIdx.x * 256 + threadIdx.x;
    if (i < n4) {
        float4 v = reinterpret_cast<const float4*>(x)[i];
        f16x4 r = {(f16)v.x, (f16)v.y, (f16)v.z, (f16)v.w};
        reinterpret_cast<f16x4*>(y)[i] = r;
    }
}

// ---------------- per-(node,relation) edge counts ---------------------------
__global__ void k_count(const int* __restrict__ dst, const int* __restrict__ et,
                        float* __restrict__ counts) {
    int e = blockIdx.x * 256 + threadIdx.x;
    if (e < NE) atomicAdd(&counts[(size_t)dst[e] * NR + et[e]], 1.0f);
}

// ---------------- MFMA GEMM: C[N,J] = A[N,K](f16) * Bt[J,K](f16)^T ----------
// 128x128 tile, 512 threads = 8 waves (2 Mx4 N); wave = 64x32 = 4x2 frags 16x16.
template<int K, typename OutT>
__global__ __launch_bounds__(512)
void k_mfma(const f16* __restrict__ A, const f16* __restrict__ Bt,
            OutT* __restrict__ C, int N, int J) {
    constexpr int KP = K + 8;                 // +16B pad: banks stride 4 -> 2-way only
    __shared__ f16 As[128 * KP];
    __shared__ f16 Bs[128 * KP];
    int tid = threadIdx.x;
    int m0 = blockIdx.y * 128;
    int n0 = blockIdx.x * 128;

    constexpr int V = K / 8;
    for (int idx = tid; idx < 128 * V; idx += 512) {
        int r = idx / V, c = idx % V;
        f16x8 va = {}, vb = {};
        if (m0 + r < N) va = *reinterpret_cast<const f16x8*>(A + (size_t)(m0 + r) * K + c * 8);
        if (n0 + r < J) vb = *reinterpret_cast<const f16x8*>(Bt + (size_t)(n0 + r) * K + c * 8);
        *reinterpret_cast<f16x8*>(&As[r * KP + c * 8]) = va;
        *reinterpret_cast<f16x8*>(&Bs[r * KP + c * 8]) = vb;
    }
    __syncthreads();

    int w = tid >> 6, lane = tid & 63;
    int wr = (w >> 2) * 64, wc = (w & 3) * 32;
    int lr = lane & 15, lk = (lane >> 4) * 8;

    f32x4 acc[4][2];
#pragma unroll
    for (int mm = 0; mm < 4; mm++)
#pragma unroll
        for (int nn = 0; nn < 2; nn++) acc[mm][nn] = (f32x4){0.f, 0.f, 0.f, 0.f};

#pragma unroll
    for (int k0 = 0; k0 < K; k0 += 32) {
        f16x8 a[4], b[2];
#pragma unroll
        for (int mm = 0; mm < 4; mm++)
            a[mm] = *reinterpret_cast<const f16x8*>(&As[(wr + mm*16 + lr) * KP + k0 + lk]);
#pragma unroll
        for (int nn = 0; nn < 2; nn++)
            b[nn] = *reinterpret_cast<const f16x8*>(&Bs[(wc + nn*16 + lr) * KP + k0 + lk]);
#pragma unroll
        for (int mm = 0; mm < 4; mm++)
#pragma unroll
            for (int nn = 0; nn < 2; nn++)
                acc[mm][nn] = __builtin_amdgcn_mfma_f32_16x16x32_f16(a[mm], b[nn], acc[mm][nn], 0, 0, 0);
    }

    int g = lane >> 4;
#pragma unroll
    for (int mm = 0; mm < 4; mm++)
#pragma unroll
        for (int nn = 0; nn < 2; nn++) {
            int col = n0 + wc + nn*16 + lr;
            if (col < J) {
#pragma unroll
                for (int q = 0; q < 4; q++) {
                    int row = m0 + wr + mm*16 + g*4 + q;
                    if (row < N) C[(size_t)row * J + col] = (OutT)acc[mm][nn][q];
                }
            }
        }
}

// ---------------- layer-1 aggregation: wave per edge, 64-wide atomics -------
__global__ void k_agg1(const int* __restrict__ ei, const int* __restrict__ et,
                       const float* __restrict__ counts, const f16* __restrict__ Y1,
                       float* __restrict__ H1) {
    int e = blockIdx.x * 4 + (threadIdx.x >> 6);
    if (e >= NE) return;
    int lane = threadIdx.x & 63;
    int s = ei[e], d = ei[NE + e], t = et[e];
    float c = counts[(size_t)d * NR + t];
    float w = 1.0f / fmaxf(c, 1.0f);
    float v = (float)Y1[(size_t)s * J1 + t * HID + lane];
    atomicAdd(&H1[(size_t)d * HID + lane], v * w);
}

// ---------------- finalize layer 1: X1h = fp16(relu(H1 + root + b1)) --------
__global__ void k_fin1(const float* __restrict__ H1, const f16* __restrict__ Y1,
                       const float* __restrict__ b1, f16* __restrict__ X1h) {
    int idx = blockIdx.x * 256 + threadIdx.x;     // n*64 + o
    if (idx >= N_NODES * HID) return;
    int n = idx >> 6, o = idx & 63;
    float v = H1[idx] + (float)Y1[(size_t)n * J1 + NR*HID + o] + b1[o];
    X1h[idx] = (f16)fmaxf(v, 0.0f);
}

// ---------------- layer-2 aggregation: 16 lanes per edge --------------------
__global__ void k_agg2(const int* __restrict__ ei, const int* __restrict__ et,
                       const float* __restrict__ counts, const float* __restrict__ Y2,
                       float* __restrict__ H2out) {
    int idx = blockIdx.x * 256 + threadIdx.x;
    int e = idx >> 4;
    if (e >= NE) return;
    int o = idx & 15;
    int s = ei[e], d = ei[NE + e], t = et[e];
    float c = counts[(size_t)d * NR + t];
    float w = 1.0f / fmaxf(c, 1.0f);
    float v = Y2[(size_t)s * J2 + t * NC + o];
    atomicAdd(&H2out[(size_t)d * NC + o], v * w);
}

// ---------------- finalize layer 2: sigmoid(H2 + root + b2) -----------------
__global__ void k_fin2(float* __restrict__ out, const float* __restrict__ Y2,
                       const float* __restrict__ b2) {
    int idx = blockIdx.x * 256 + threadIdx.x;     // n*16 + o
    if (idx >= N_NODES * NC) return;
    int n = idx >> 4, o = idx & 15;
    float v = out[idx] + Y2[(size_t)n * J2 + NR*NC + o] + b2[o];
    out[idx] = 1.0f / (1.0f + expf(-v));
}

extern "C" void kernel_launch(void* const* d_in, const int* in_sizes, int n_in,
                              void* d_out, int out_size, void* d_ws, size_t ws_size,
                              hipStream_t stream) {
    const float* emb   = (const float*)d_in[0];
    const float* W1    = (const float*)d_in[1];
    const float* root1 = (const float*)d_in[2];
    const float* b1    = (const float*)d_in[3];
    const float* W2    = (const float*)d_in[4];
    const float* root2 = (const float*)d_in[5];
    const float* b2    = (const float*)d_in[6];
    const int*   ei    = (const int*)d_in[7];    // [2, NE]: src then dst
    const int*   et    = (const int*)d_in[8];
    float* out = (float*)d_out;

    char* ws = (char*)d_ws;
    // ws layout (bytes), peak 131.5 MB:
    //   counts:   0          .. 3,200,000     (800000 f32)
    //   Bt1:      3,200,000  .. +278,528      (1088x128 f16)
    //   Bt2:      3,478,528  .. +34,816       (272x64 f16)
    //   embh/H1:  3,513,344  .. +12,800,000   (aliased: embh f16 dies before H1 born)
    //   X1h:      16,313,344 .. +6,400,000    (50000x64 f16)
    //   Y1/Y2:    22,713,344 .. +108,800,000  (Y1 f16 50000x1088; Y2 f32 50000x272 after fin1)
    float* counts = (float*)(ws + 0);
    f16*   Bt1    = (f16*)(ws + 3200000);
    f16*   Bt2    = (f16*)(ws + 3478528);
    f16*   embh   = (f16*)(ws + 3513344);
    float* H1     = (float*)(ws + 3513344);      // aliases embh (disjoint lifetime)
    f16*   X1h    = (f16*)(ws + 16313344);
    f16*   Y1     = (f16*)(ws + 22713344);
    float* Y2     = (float*)(ws + 22713344);     // aliases Y1 (dead after fin1)

    hipMemsetAsync(counts, 0, 3200000, stream);
    hipMemsetAsync(out, 0, (size_t)N_NODES * NC * sizeof(float), stream);

    k_build_B<<<613, 256, 0, stream>>>(W1, root1, W2, root2, Bt1, Bt2);
    k_cast<<<(N_NODES * EMB / 4 + 255) / 256, 256, 0, stream>>>(emb, embh, N_NODES * EMB / 4);
    k_count<<<(NE + 255) / 256, 256, 0, stream>>>(ei + NE, et, counts);

    dim3 g1((J1 + 127) / 128, (N_NODES + 127) / 128);   // 9 x 391
    k_mfma<EMB, f16><<<g1, 512, 0, stream>>>(embh, Bt1, Y1, N_NODES, J1);

    hipMemsetAsync(H1, 0, 12800000, stream);            // after gemm1 (embh alias)

    k_agg1<<<NE / 4, 256, 0, stream>>>(ei, et, counts, Y1, H1);
    k_fin1<<<(N_NODES * HID + 255) / 256, 256, 0, stream>>>(H1, Y1, b1, X1h);

    dim3 g2((J2 + 127) / 128, (N_NODES + 127) / 128);   // 3 x 391
    k_mfma<HID, float><<<g2, 512, 0, stream>>>(X1h, Bt2, Y2, N_NODES, J2);

    k_agg2<<<(NE * NC) / 256, 256, 0, stream>>>(ei, et, counts, Y2, out);
    k_fin2<<<(N_NODES * NC + 255) / 256, 256, 0, stream>>>(out, Y2, b2);
}

// Round 4
// 213.717 us; speedup vs baseline: 2.7141x; 1.6747x over previous
//
#include <hip/hip_runtime.h>
#include <hip/hip_fp16.h>

#define N_NODES 50000
#define EMB 128
#define HID 64
#define NR 16
#define NC 16
#define NE 800000
#define J1 (NR*HID + HID)   /* 1088 */
#define J2 (NR*NC + NC)     /* 272  */
#define CAP 64              /* max in-degree bucket capacity (deg~Poisson(16)) */

typedef _Float16 f16;
typedef __attribute__((ext_vector_type(8))) _Float16 f16x8;
typedef __attribute__((ext_vector_type(4))) _Float16 f16x4;
typedef __attribute__((ext_vector_type(4))) float f32x4;

// ---------------- build packed transposed fp16 B: Bt1[1088][128], Bt2[272][64]
__global__ void k_build_B(const float* __restrict__ W1, const float* __restrict__ root1,
                          const float* __restrict__ W2, const float* __restrict__ root2,
                          f16* __restrict__ Bt1, f16* __restrict__ Bt2) {
    int idx = blockIdx.x * 256 + threadIdx.x;
    const int total1 = J1 * EMB;   // 139264
    const int total2 = J2 * HID;   // 17408
    if (idx < total1) {
        int j = idx / EMB, i = idx % EMB;
        float v = (j < NR*HID) ? W1[((size_t)(j >> 6) * EMB + i) * HID + (j & 63)]
                               : root1[i * HID + (j - NR*HID)];
        Bt1[idx] = (f16)v;
    } else if (idx < total1 + total2) {
        int t = idx - total1;
        int j = t / HID, i = t % HID;
        float v = (j < NR*NC) ? W2[((size_t)(j >> 4) * HID + i) * NC + (j & 15)]
                              : root2[i * NC + (j - NR*NC)];
        Bt2[t] = (f16)v;
    }
}

// ---------------- fp32 -> fp16 cast (vectorized) ----------------------------
__global__ void k_cast(const float* __restrict__ x, f16* __restrict__ y, int n4) {
    int i = blockIdx.x * 256 + threadIdx.x;
    if (i < n4) {
        float4 v = reinterpret_cast<const float4*>(x)[i];
        f16x4 r = {(f16)v.x, (f16)v.y, (f16)v.z, (f16)v.w};
        reinterpret_cast<f16x4*>(y)[i] = r;
    }
}

// ---------------- per-(node,relation) edge counts (int) ---------------------
__global__ void k_count(const int* __restrict__ dst, const int* __restrict__ et,
                        int* __restrict__ counts) {
    int e = blockIdx.x * 256 + threadIdx.x;
    if (e < NE) atomicAdd(&counts[(size_t)dst[e] * NR + et[e]], 1);
}

// ---------------- scatter edges into per-dst buckets ------------------------
// entry = src(16b) | type<<16 (4b) | count<<20 (8b)
__global__ void k_scatter(const int* __restrict__ ei, const int* __restrict__ et,
                          const int* __restrict__ counts, int* __restrict__ cur,
                          unsigned* __restrict__ packed) {
    int e = blockIdx.x * 256 + threadIdx.x;
    if (e >= NE) return;
    int s = ei[e], d = ei[NE + e], t = et[e];
    int c = counts[(size_t)d * NR + t]; if (c > 255) c = 255;
    int pos = atomicAdd(&cur[d], 1);
    if (pos < CAP)
        packed[(size_t)d * CAP + pos] = (unsigned)s | ((unsigned)t << 16) | ((unsigned)c << 20);
}

// ---------------- MFMA GEMM: C[N,J] = A[N,K](f16) * Bt[J,K](f16)^T ----------
template<int K, typename OutT>
__global__ __launch_bounds__(512)
void k_mfma(const f16* __restrict__ A, const f16* __restrict__ Bt,
            OutT* __restrict__ C, int N, int J) {
    constexpr int KP = K + 8;
    __shared__ f16 As[128 * KP];
    __shared__ f16 Bs[128 * KP];
    int tid = threadIdx.x;
    int m0 = blockIdx.y * 128;
    int n0 = blockIdx.x * 128;

    constexpr int V = K / 8;
    for (int idx = tid; idx < 128 * V; idx += 512) {
        int r = idx / V, c = idx % V;
        f16x8 va = {}, vb = {};
        if (m0 + r < N) va = *reinterpret_cast<const f16x8*>(A + (size_t)(m0 + r) * K + c * 8);
        if (n0 + r < J) vb = *reinterpret_cast<const f16x8*>(Bt + (size_t)(n0 + r) * K + c * 8);
        *reinterpret_cast<f16x8*>(&As[r * KP + c * 8]) = va;
        *reinterpret_cast<f16x8*>(&Bs[r * KP + c * 8]) = vb;
    }
    __syncthreads();

    int w = tid >> 6, lane = tid & 63;
    int wr = (w >> 2) * 64, wc = (w & 3) * 32;
    int lr = lane & 15, lk = (lane >> 4) * 8;

    f32x4 acc[4][2];
#pragma unroll
    for (int mm = 0; mm < 4; mm++)
#pragma unroll
        for (int nn = 0; nn < 2; nn++) acc[mm][nn] = (f32x4){0.f, 0.f, 0.f, 0.f};

#pragma unroll
    for (int k0 = 0; k0 < K; k0 += 32) {
        f16x8 a[4], b[2];
#pragma unroll
        for (int mm = 0; mm < 4; mm++)
            a[mm] = *reinterpret_cast<const f16x8*>(&As[(wr + mm*16 + lr) * KP + k0 + lk]);
#pragma unroll
        for (int nn = 0; nn < 2; nn++)
            b[nn] = *reinterpret_cast<const f16x8*>(&Bs[(wc + nn*16 + lr) * KP + k0 + lk]);
#pragma unroll
        for (int mm = 0; mm < 4; mm++)
#pragma unroll
            for (int nn = 0; nn < 2; nn++)
                acc[mm][nn] = __builtin_amdgcn_mfma_f32_16x16x32_f16(a[mm], b[nn], acc[mm][nn], 0, 0, 0);
    }

    int g = lane >> 4;
#pragma unroll
    for (int mm = 0; mm < 4; mm++)
#pragma unroll
        for (int nn = 0; nn < 2; nn++) {
            int col = n0 + wc + nn*16 + lr;
            if (col < J) {
#pragma unroll
                for (int q = 0; q < 4; q++) {
                    int row = m0 + wr + mm*16 + g*4 + q;
                    if (row < N) C[(size_t)row * J + col] = (OutT)acc[mm][nn][q];
                }
            }
        }
}

// ---------------- fused layer-1 aggregation + finalize -----------------------
// wave per node, lane = output channel; bucket entries broadcast via shfl.
// deg is wave-uniform -> identical trip counts -> all lanes active at each shfl.
__global__ __launch_bounds__(256)
void k_agg1f(const int* __restrict__ cur, const unsigned* __restrict__ packed,
             const f16* __restrict__ Y1, const float* __restrict__ b1,
             f16* __restrict__ X1h) {
    int n = (blockIdx.x * 256 + threadIdx.x) >> 6;
    if (n >= N_NODES) return;
    int lane = threadIdx.x & 63;
    int deg = cur[n]; if (deg > CAP) deg = CAP;
    const unsigned* pk = packed + (size_t)n * CAP;
    unsigned my = pk[lane];                    // entries beyond deg: garbage, never shfl'd
    float acc = 0.f;
    int i = 0;
    for (; i + 4 <= deg; i += 4) {
        unsigned e0 = __shfl(my, i), e1 = __shfl(my, i + 1),
                 e2 = __shfl(my, i + 2), e3 = __shfl(my, i + 3);
        float v0 = (1.0f / fmaxf((float)(e0 >> 20), 1.0f)) *
                   (float)Y1[(size_t)(e0 & 0xFFFF) * J1 + ((e0 >> 16) & 15) * HID + lane];
        float v1 = (1.0f / fmaxf((float)(e1 >> 20), 1.0f)) *
                   (float)Y1[(size_t)(e1 & 0xFFFF) * J1 + ((e1 >> 16) & 15) * HID + lane];
        float v2 = (1.0f / fmaxf((float)(e2 >> 20), 1.0f)) *
                   (float)Y1[(size_t)(e2 & 0xFFFF) * J1 + ((e2 >> 16) & 15) * HID + lane];
        float v3 = (1.0f / fmaxf((float)(e3 >> 20), 1.0f)) *
                   (float)Y1[(size_t)(e3 & 0xFFFF) * J1 + ((e3 >> 16) & 15) * HID + lane];
        acc += v0; acc += v1; acc += v2; acc += v3;
    }
    for (; i < deg; i++) {
        unsigned e0 = __shfl(my, i);
        acc += (1.0f / fmaxf((float)(e0 >> 20), 1.0f)) *
               (float)Y1[(size_t)(e0 & 0xFFFF) * J1 + ((e0 >> 16) & 15) * HID + lane];
    }
    float v = acc + (float)Y1[(size_t)n * J1 + NR*HID + lane] + b1[lane];
    X1h[(size_t)n * HID + lane] = (f16)fmaxf(v, 0.0f);
}

// ---------------- fused layer-2 aggregation + finalize -----------------------
// wave per node: 4 edge-groups x 16 channels. FIX vs r3: uniform trip count —
// all lanes run i = 0,4,...,<deg and shfl(my, i+grp) with ALL lanes active;
// only the load/accumulate is predicated (idx = i+grp <= 63 always).
__global__ __launch_bounds__(256)
void k_agg2f(const int* __restrict__ cur, const unsigned* __restrict__ packed,
             const float* __restrict__ Y2, const float* __restrict__ b2,
             float* __restrict__ out) {
    int n = (blockIdx.x * 256 + threadIdx.x) >> 6;
    if (n >= N_NODES) return;
    int lane = threadIdx.x & 63;
    int o = lane & 15, grp = lane >> 4;
    int deg = cur[n]; if (deg > CAP) deg = CAP;
    const unsigned* pk = packed + (size_t)n * CAP;
    unsigned my = pk[lane];
    float acc = 0.f;
    for (int i = 0; i < deg; i += 4) {          // wave-uniform bound
        int idx = i + grp;                      // i <= 60, grp <= 3 -> idx <= 63
        unsigned en = __shfl(my, idx);          // all 64 lanes active here
        if (idx < deg)
            acc += (1.0f / fmaxf((float)(en >> 20), 1.0f)) *
                   Y2[(size_t)(en & 0xFFFF) * J2 + ((en >> 16) & 15) * NC + o];
    }
    acc += __shfl_xor(acc, 16);
    acc += __shfl_xor(acc, 32);
    if (grp == 0) {
        float v = acc + Y2[(size_t)n * J2 + NR*NC + o] + b2[o];
        out[(size_t)n * NC + o] = 1.0f / (1.0f + expf(-v));
    }
}

extern "C" void kernel_launch(void* const* d_in, const int* in_sizes, int n_in,
                              void* d_out, int out_size, void* d_ws, size_t ws_size,
                              hipStream_t stream) {
    const float* emb   = (const float*)d_in[0];
    const float* W1    = (const float*)d_in[1];
    const float* root1 = (const float*)d_in[2];
    const float* b1    = (const float*)d_in[3];
    const float* W2    = (const float*)d_in[4];
    const float* root2 = (const float*)d_in[5];
    const float* b2    = (const float*)d_in[6];
    const int*   ei    = (const int*)d_in[7];    // [2, NE]: src then dst
    const int*   et    = (const int*)d_in[8];
    float* out = (float*)d_out;

    char* ws = (char*)d_ws;
    // ws layout (bytes), total 138,113,344:
    //   cur:      0          .. +200,000      (50000 i32)
    //   Bt1:      200,000    .. +278,528      (1088x128 f16)
    //   Bt2:      478,528    .. +34,816       (272x64 f16)
    //   counts:   513,344    .. +3,200,000    (50000x16 i32)
    //   packed:   3,713,344  .. +12,800,000   (50000x64 u32 buckets)
    //   embh/X1h: 16,513,344 .. +12,800,000   (embh f16 dies at gemm1; X1h aliases)
    //   Y1/Y2:    29,313,344 .. +108,800,000  (Y1 f16 [50000][1088]; Y2 f32 [50000][272])
    int*      cur    = (int*)(ws + 0);
    f16*      Bt1    = (f16*)(ws + 200000);
    f16*      Bt2    = (f16*)(ws + 478528);
    int*      counts = (int*)(ws + 513344);
    unsigned* packed = (unsigned*)(ws + 3713344);
    f16*      embh   = (f16*)(ws + 16513344);
    f16*      X1h    = (f16*)(ws + 16513344);    // aliases embh (disjoint lifetime)
    f16*      Y1     = (f16*)(ws + 29313344);
    float*    Y2     = (float*)(ws + 29313344);  // aliases Y1 (dead after agg1f)

    hipMemsetAsync(cur, 0, 200000, stream);
    hipMemsetAsync(counts, 0, 3200000, stream);

    k_build_B<<<613, 256, 0, stream>>>(W1, root1, W2, root2, Bt1, Bt2);
    k_cast<<<(N_NODES * EMB / 4 + 255) / 256, 256, 0, stream>>>(emb, embh, N_NODES * EMB / 4);
    k_count<<<(NE + 255) / 256, 256, 0, stream>>>(ei + NE, et, counts);
    k_scatter<<<(NE + 255) / 256, 256, 0, stream>>>(ei, et, counts, cur, packed);

    dim3 g1((J1 + 127) / 128, (N_NODES + 127) / 128);   // 9 x 391
    k_mfma<EMB, f16><<<g1, 512, 0, stream>>>(embh, Bt1, Y1, N_NODES, J1);

    k_agg1f<<<(N_NODES * 64 + 255) / 256, 256, 0, stream>>>(cur, packed, Y1, b1, X1h);

    dim3 g2((J2 + 127) / 128, (N_NODES + 127) / 128);   // 3 x 391
    k_mfma<HID, float><<<g2, 512, 0, stream>>>(X1h, Bt2, Y2, N_NODES, J2);

    k_agg2f<<<(N_NODES * 64 + 255) / 256, 256, 0, stream>>>(cur, packed, Y2, b2, out);
}

// Round 5
// 193.738 us; speedup vs baseline: 2.9940x; 1.1031x over previous
//
#include <hip/hip_runtime.h>
#include <hip/hip_fp16.h>

#define N_NODES 50000
#define EMB 128
#define HID 64
#define NR 16
#define NC 16
#define NE 800000
#define J1 (NR*HID + HID)   /* 1088 */
#define J2 (NR*NC + NC)     /* 272  */
#define CAP 64              /* max in-degree bucket capacity (deg~Poisson(16)) */

typedef _Float16 f16;
typedef __attribute__((ext_vector_type(8))) _Float16 f16x8;
typedef __attribute__((ext_vector_type(4))) _Float16 f16x4;
typedef __attribute__((ext_vector_type(4))) float f32x4;

// ---------------- build packed transposed fp16 B: Bt1[1088][128], Bt2[272][64]
__global__ void k_build_B(const float* __restrict__ W1, const float* __restrict__ root1,
                          const float* __restrict__ W2, const float* __restrict__ root2,
                          f16* __restrict__ Bt1, f16* __restrict__ Bt2) {
    int idx = blockIdx.x * 256 + threadIdx.x;
    const int total1 = J1 * EMB;   // 139264
    const int total2 = J2 * HID;   // 17408
    if (idx < total1) {
        int j = idx / EMB, i = idx % EMB;
        float v = (j < NR*HID) ? W1[((size_t)(j >> 6) * EMB + i) * HID + (j & 63)]
                               : root1[i * HID + (j - NR*HID)];
        Bt1[idx] = (f16)v;
    } else if (idx < total1 + total2) {
        int t = idx - total1;
        int j = t / HID, i = t % HID;
        float v = (j < NR*NC) ? W2[((size_t)(j >> 4) * HID + i) * NC + (j & 15)]
                              : root2[i * NC + (j - NR*NC)];
        Bt2[t] = (f16)v;
    }
}

// ---------------- fp32 -> fp16 cast (vectorized) ----------------------------
__global__ void k_cast(const float* __restrict__ x, f16* __restrict__ y, int n4) {
    int i = blockIdx.x * 256 + threadIdx.x;
    if (i < n4) {
        float4 v = reinterpret_cast<const float4*>(x)[i];
        f16x4 r = {(f16)v.x, (f16)v.y, (f16)v.z, (f16)v.w};
        reinterpret_cast<f16x4*>(y)[i] = r;
    }
}

// ---------------- scatter edges into per-dst buckets ------------------------
// entry = src(16b) | type<<16 (4b). Counts are derived later via ballot.
__global__ void k_scatter(const int* __restrict__ ei, const int* __restrict__ et,
                          int* __restrict__ cur, unsigned* __restrict__ packed) {
    int e = blockIdx.x * 256 + threadIdx.x;
    if (e >= NE) return;
    int s = ei[e], d = ei[NE + e], t = et[e];
    int pos = atomicAdd(&cur[d], 1);
    if (pos < CAP)
        packed[(size_t)d * CAP + pos] = (unsigned)s | ((unsigned)t << 16);
}

// ---------------- MFMA GEMM: C[N,J] = A[N,K](f16) * Bt[J,K](f16)^T ----------
template<int K, typename OutT>
__global__ __launch_bounds__(512)
void k_mfma(const f16* __restrict__ A, const f16* __restrict__ Bt,
            OutT* __restrict__ C, int N, int J) {
    constexpr int KP = K + 8;
    __shared__ f16 As[128 * KP];
    __shared__ f16 Bs[128 * KP];
    int tid = threadIdx.x;
    int m0 = blockIdx.y * 128;
    int n0 = blockIdx.x * 128;

    constexpr int V = K / 8;
    for (int idx = tid; idx < 128 * V; idx += 512) {
        int r = idx / V, c = idx % V;
        f16x8 va = {}, vb = {};
        if (m0 + r < N) va = *reinterpret_cast<const f16x8*>(A + (size_t)(m0 + r) * K + c * 8);
        if (n0 + r < J) vb = *reinterpret_cast<const f16x8*>(Bt + (size_t)(n0 + r) * K + c * 8);
        *reinterpret_cast<f16x8*>(&As[r * KP + c * 8]) = va;
        *reinterpret_cast<f16x8*>(&Bs[r * KP + c * 8]) = vb;
    }
    __syncthreads();

    int w = tid >> 6, lane = tid & 63;
    int wr = (w >> 2) * 64, wc = (w & 3) * 32;
    int lr = lane & 15, lk = (lane >> 4) * 8;

    f32x4 acc[4][2];
#pragma unroll
    for (int mm = 0; mm < 4; mm++)
#pragma unroll
        for (int nn = 0; nn < 2; nn++) acc[mm][nn] = (f32x4){0.f, 0.f, 0.f, 0.f};

#pragma unroll
    for (int k0 = 0; k0 < K; k0 += 32) {
        f16x8 a[4], b[2];
#pragma unroll
        for (int mm = 0; mm < 4; mm++)
            a[mm] = *reinterpret_cast<const f16x8*>(&As[(wr + mm*16 + lr) * KP + k0 + lk]);
#pragma unroll
        for (int nn = 0; nn < 2; nn++)
            b[nn] = *reinterpret_cast<const f16x8*>(&Bs[(wc + nn*16 + lr) * KP + k0 + lk]);
#pragma unroll
        for (int mm = 0; mm < 4; mm++)
#pragma unroll
            for (int nn = 0; nn < 2; nn++)
                acc[mm][nn] = __builtin_amdgcn_mfma_f32_16x16x32_f16(a[mm], b[nn], acc[mm][nn], 0, 0, 0);
    }

    int g = lane >> 4;
#pragma unroll
    for (int mm = 0; mm < 4; mm++)
#pragma unroll
        for (int nn = 0; nn < 2; nn++) {
            int col = n0 + wc + nn*16 + lr;
            if (col < J) {
#pragma unroll
                for (int q = 0; q < 4; q++) {
                    int row = m0 + wr + mm*16 + g*4 + q;
                    if (row < N) C[(size_t)row * J + col] = (OutT)acc[mm][nn][q];
                }
            }
        }
}

// ---------------- fused layer-1 aggregation + finalize -----------------------
// wave per node, lane = output channel. Per-rel counts derived via 16 ballots;
// lanes 0..15 hold w_r = 1/max(cnt_r,1); per-edge weight via one extra shfl.
// deg is wave-uniform -> identical trip counts -> all lanes active at each shfl.
__global__ __launch_bounds__(256)
void k_agg1f(const int* __restrict__ cur, const unsigned* __restrict__ packed,
             const f16* __restrict__ Y1, const float* __restrict__ b1,
             f16* __restrict__ X1h) {
    int n = (blockIdx.x * 256 + threadIdx.x) >> 6;
    if (n >= N_NODES) return;
    int lane = threadIdx.x & 63;
    int deg = cur[n]; if (deg > CAP) deg = CAP;
    const unsigned* pk = packed + (size_t)n * CAP;
    unsigned my = pk[lane];                    // lane >= deg: stale garbage, masked below
    int tp = (my >> 16) & 15;
    float wreg = 0.f;
#pragma unroll
    for (int r = 0; r < 16; r++) {
        unsigned long long b = __ballot(lane < deg && tp == r);
        if (lane == r) wreg = 1.0f / fmaxf((float)__popcll(b), 1.0f);
    }
    float acc = 0.f;
    int i = 0;
    for (; i + 4 <= deg; i += 4) {
        unsigned e0 = __shfl(my, i), e1 = __shfl(my, i + 1),
                 e2 = __shfl(my, i + 2), e3 = __shfl(my, i + 3);
        float w0 = __shfl(wreg, (int)(e0 >> 16)), w1 = __shfl(wreg, (int)(e1 >> 16)),
              w2 = __shfl(wreg, (int)(e2 >> 16)), w3 = __shfl(wreg, (int)(e3 >> 16));
        float v0 = w0 * (float)Y1[(size_t)(e0 & 0xFFFF) * J1 + (e0 >> 16) * HID + lane];
        float v1 = w1 * (float)Y1[(size_t)(e1 & 0xFFFF) * J1 + (e1 >> 16) * HID + lane];
        float v2 = w2 * (float)Y1[(size_t)(e2 & 0xFFFF) * J1 + (e2 >> 16) * HID + lane];
        float v3 = w3 * (float)Y1[(size_t)(e3 & 0xFFFF) * J1 + (e3 >> 16) * HID + lane];
        acc += v0; acc += v1; acc += v2; acc += v3;
    }
    for (; i < deg; i++) {
        unsigned e0 = __shfl(my, i);
        float w0 = __shfl(wreg, (int)(e0 >> 16));
        acc += w0 * (float)Y1[(size_t)(e0 & 0xFFFF) * J1 + (e0 >> 16) * HID + lane];
    }
    float v = acc + (float)Y1[(size_t)n * J1 + NR*HID + lane] + b1[lane];
    X1h[(size_t)n * HID + lane] = (f16)fmaxf(v, 0.0f);
}

// ---------------- fused layer-2 aggregation + finalize -----------------------
// wave per node: 4 edge-groups x 16 channels, uniform trip count, ballot counts.
__global__ __launch_bounds__(256)
void k_agg2f(const int* __restrict__ cur, const unsigned* __restrict__ packed,
             const float* __restrict__ Y2, const float* __restrict__ b2,
             float* __restrict__ out) {
    int n = (blockIdx.x * 256 + threadIdx.x) >> 6;
    if (n >= N_NODES) return;
    int lane = threadIdx.x & 63;
    int o = lane & 15, grp = lane >> 4;
    int deg = cur[n]; if (deg > CAP) deg = CAP;
    const unsigned* pk = packed + (size_t)n * CAP;
    unsigned my = pk[lane];
    int tp = (my >> 16) & 15;
    float wreg = 0.f;
#pragma unroll
    for (int r = 0; r < 16; r++) {
        unsigned long long b = __ballot(lane < deg && tp == r);
        if (lane == r) wreg = 1.0f / fmaxf((float)__popcll(b), 1.0f);
    }
    float acc = 0.f;
    for (int i = 0; i < deg; i += 4) {          // wave-uniform bound
        int idx = i + grp;                      // i <= 60, grp <= 3 -> idx <= 63
        unsigned en = __shfl(my, idx);          // all 64 lanes active here
        // en may be stale for idx >= deg; shfl index wraps mod 64, result unused
        float w = __shfl(wreg, (int)(en >> 16) & 63);
        if (idx < deg)
            acc += w * Y2[(size_t)(en & 0xFFFF) * J2 + ((en >> 16) & 15) * NC + o];
    }
    acc += __shfl_xor(acc, 16);
    acc += __shfl_xor(acc, 32);
    if (grp == 0) {
        float v = acc + Y2[(size_t)n * J2 + NR*NC + o] + b2[o];
        out[(size_t)n * NC + o] = 1.0f / (1.0f + expf(-v));
    }
}

extern "C" void kernel_launch(void* const* d_in, const int* in_sizes, int n_in,
                              void* d_out, int out_size, void* d_ws, size_t ws_size,
                              hipStream_t stream) {
    const float* emb   = (const float*)d_in[0];
    const float* W1    = (const float*)d_in[1];
    const float* root1 = (const float*)d_in[2];
    const float* b1    = (const float*)d_in[3];
    const float* W2    = (const float*)d_in[4];
    const float* root2 = (const float*)d_in[5];
    const float* b2    = (const float*)d_in[6];
    const int*   ei    = (const int*)d_in[7];    // [2, NE]: src then dst
    const int*   et    = (const int*)d_in[8];
    float* out = (float*)d_out;

    char* ws = (char*)d_ws;
    // ws layout (bytes), total 134,913,344:
    //   cur:      0          .. +200,000      (50000 i32)
    //   Bt1:      200,000    .. +278,528      (1088x128 f16)
    //   Bt2:      478,528    .. +34,816       (272x64 f16)
    //   packed:   513,344    .. +12,800,000   (50000x64 u32 buckets)
    //   embh/X1h: 13,313,344 .. +12,800,000   (embh f16 dies at gemm1; X1h aliases)
    //   Y1/Y2:    26,113,344 .. +108,800,000  (Y1 f16 [50000][1088]; Y2 f32 [50000][272])
    int*      cur    = (int*)(ws + 0);
    f16*      Bt1    = (f16*)(ws + 200000);
    f16*      Bt2    = (f16*)(ws + 478528);
    unsigned* packed = (unsigned*)(ws + 513344);
    f16*      embh   = (f16*)(ws + 13313344);
    f16*      X1h    = (f16*)(ws + 13313344);    // aliases embh (disjoint lifetime)
    f16*      Y1     = (f16*)(ws + 26113344);
    float*    Y2     = (float*)(ws + 26113344);  // aliases Y1 (dead after agg1f)

    hipMemsetAsync(cur, 0, 200000, stream);

    k_build_B<<<613, 256, 0, stream>>>(W1, root1, W2, root2, Bt1, Bt2);
    k_cast<<<(N_NODES * EMB / 4 + 255) / 256, 256, 0, stream>>>(emb, embh, N_NODES * EMB / 4);
    k_scatter<<<(NE + 255) / 256, 256, 0, stream>>>(ei, et, cur, packed);

    dim3 g1((J1 + 127) / 128, (N_NODES + 127) / 128);   // 9 x 391
    k_mfma<EMB, f16><<<g1, 512, 0, stream>>>(embh, Bt1, Y1, N_NODES, J1);

    k_agg1f<<<(N_NODES * 64 + 255) / 256, 256, 0, stream>>>(cur, packed, Y1, b1, X1h);

    dim3 g2((J2 + 127) / 128, (N_NODES + 127) / 128);   // 3 x 391
    k_mfma<HID, float><<<g2, 512, 0, stream>>>(X1h, Bt2, Y2, N_NODES, J2);

    k_agg2f<<<(N_NODES * 64 + 255) / 256, 256, 0, stream>>>(cur, packed, Y2, b2, out);
}

// Round 6
// 155.949 us; speedup vs baseline: 3.7195x; 1.2423x over previous
//
#include <hip/hip_runtime.h>
#include <hip/hip_fp16.h>

#define N_NODES 50000
#define EMB 128
#define HID 64
#define NR 16
#define NC 16
#define NE 800000
#define J1 (NR*HID + HID)   /* 1088 = 17*64 */
#define J2 (NR*NC + NC)     /* 272  = 17*16 */
#define CAP 64              /* bucket capacity (deg~Poisson(16)) */

typedef _Float16 f16;
typedef __attribute__((ext_vector_type(8))) _Float16 f16x8;
typedef __attribute__((ext_vector_type(4))) _Float16 f16x4;
typedef __attribute__((ext_vector_type(4))) float f32x4;

// ---- fused pre-pass: [cast emb->f16 | build Bt1/Bt2 | zero cur] ------------
#define PRE_CAST_BLK 6250              /* 1,600,000 f16x4 groups */
#define PRE_BB_BLK 613
__global__ __launch_bounds__(256)
void k_pre(const float* __restrict__ emb, const float* __restrict__ W1,
           const float* __restrict__ root1, const float* __restrict__ W2,
           const float* __restrict__ root2, f16* __restrict__ embh,
           f16* __restrict__ Bt1, f16* __restrict__ Bt2, int* __restrict__ cur) {
    int bx = blockIdx.x, tid = threadIdx.x;
    if (bx < PRE_CAST_BLK) {
        int i = bx * 256 + tid;
        if (i < N_NODES * EMB / 4) {
            float4 v = reinterpret_cast<const float4*>(emb)[i];
            f16x4 r = {(f16)v.x, (f16)v.y, (f16)v.z, (f16)v.w};
            reinterpret_cast<f16x4*>(embh)[i] = r;
        }
    } else if (bx < PRE_CAST_BLK + PRE_BB_BLK) {
        int idx = (bx - PRE_CAST_BLK) * 256 + tid;
        const int total1 = J1 * EMB;   // 139264
        const int total2 = J2 * HID;   // 17408
        if (idx < total1) {
            int j = idx / EMB, i = idx % EMB;
            float v = (j < NR*HID) ? W1[((size_t)(j >> 6) * EMB + i) * HID + (j & 63)]
                                   : root1[i * HID + (j - NR*HID)];
            Bt1[idx] = (f16)v;
        } else if (idx < total1 + total2) {
            int t = idx - total1;
            int j = t / HID, i = t % HID;
            float v = (j < NR*NC) ? W2[((size_t)(j >> 4) * HID + i) * NC + (j & 15)]
                                  : root2[i * NC + (j - NR*NC)];
            Bt2[t] = (f16)v;
        }
    } else {
        int i = (bx - PRE_CAST_BLK - PRE_BB_BLK) * 256 + tid;
        if (i < N_NODES) cur[i] = 0;
    }
}

// ---- hybrid: GEMM1 (Y1 = embh @ Bt1^T) interleaved with edge scatter -------
// 13-block groups: r<9 -> gemm tile (m0=g*128, n0=r*128); r>=9 -> scatter.
// entry = src*17 + type  (Y1 row index / 64).
__global__ __launch_bounds__(512)
void k_g1s(const f16* __restrict__ A, const f16* __restrict__ Bt,
           f16* __restrict__ C, const int* __restrict__ ei,
           const int* __restrict__ et, int* __restrict__ cur,
           unsigned* __restrict__ packed) {
    constexpr int K = EMB, KP = K + 8;
    __shared__ f16 As[128 * KP];
    __shared__ f16 Bs[128 * KP];
    int g13 = blockIdx.x / 13, r = blockIdx.x % 13;
    int tid = threadIdx.x;

    if (r >= 9) {                       // ---- scatter path ----
        int e = (g13 * 4 + (r - 9)) * 512 + tid;
        if (e < NE) {
            int s = ei[e], d = ei[NE + e], t = et[e];
            int pos = atomicAdd(&cur[d], 1);
            if (pos < CAP)
                packed[(size_t)d * CAP + pos] = (unsigned)(s * 17 + t);
        }
        return;
    }
    // ---- gemm path: N=N_NODES rows, J=J1 cols ----
    int m0 = g13 * 128, n0 = r * 128;
    constexpr int V = K / 8;
    for (int idx = tid; idx < 128 * V; idx += 512) {
        int rr = idx / V, c = idx % V;
        f16x8 va = {}, vb = {};
        if (m0 + rr < N_NODES) va = *reinterpret_cast<const f16x8*>(A + (size_t)(m0 + rr) * K + c * 8);
        if (n0 + rr < J1)      vb = *reinterpret_cast<const f16x8*>(Bt + (size_t)(n0 + rr) * K + c * 8);
        *reinterpret_cast<f16x8*>(&As[rr * KP + c * 8]) = va;
        *reinterpret_cast<f16x8*>(&Bs[rr * KP + c * 8]) = vb;
    }
    __syncthreads();

    int w = tid >> 6, lane = tid & 63;
    int wr = (w >> 2) * 64, wc = (w & 3) * 32;
    int lr = lane & 15, lk = (lane >> 4) * 8;

    f32x4 acc[4][2];
#pragma unroll
    for (int mm = 0; mm < 4; mm++)
#pragma unroll
        for (int nn = 0; nn < 2; nn++) acc[mm][nn] = (f32x4){0.f, 0.f, 0.f, 0.f};

#pragma unroll
    for (int k0 = 0; k0 < K; k0 += 32) {
        f16x8 a[4], b[2];
#pragma unroll
        for (int mm = 0; mm < 4; mm++)
            a[mm] = *reinterpret_cast<const f16x8*>(&As[(wr + mm*16 + lr) * KP + k0 + lk]);
#pragma unroll
        for (int nn = 0; nn < 2; nn++)
            b[nn] = *reinterpret_cast<const f16x8*>(&Bs[(wc + nn*16 + lr) * KP + k0 + lk]);
#pragma unroll
        for (int mm = 0; mm < 4; mm++)
#pragma unroll
            for (int nn = 0; nn < 2; nn++)
                acc[mm][nn] = __builtin_amdgcn_mfma_f32_16x16x32_f16(a[mm], b[nn], acc[mm][nn], 0, 0, 0);
    }

    int g = lane >> 4;
#pragma unroll
    for (int mm = 0; mm < 4; mm++)
#pragma unroll
        for (int nn = 0; nn < 2; nn++) {
            int col = n0 + wc + nn*16 + lr;
            if (col < J1) {
#pragma unroll
                for (int q = 0; q < 4; q++) {
                    int row = m0 + wr + mm*16 + g*4 + q;
                    if (row < N_NODES) C[(size_t)row * J1 + col] = (f16)acc[mm][nn][q];
                }
            }
        }
}

// ---- MFMA GEMM for layer 2 (unchanged structure) ---------------------------
template<int K, typename OutT>
__global__ __launch_bounds__(512)
void k_mfma(const f16* __restrict__ A, const f16* __restrict__ Bt,
            OutT* __restrict__ C, int N, int J) {
    constexpr int KP = K + 8;
    __shared__ f16 As[128 * KP];
    __shared__ f16 Bs[128 * KP];
    int tid = threadIdx.x;
    int m0 = blockIdx.y * 128;
    int n0 = blockIdx.x * 128;

    constexpr int V = K / 8;
    for (int idx = tid; idx < 128 * V; idx += 512) {
        int r = idx / V, c = idx % V;
        f16x8 va = {}, vb = {};
        if (m0 + r < N) va = *reinterpret_cast<const f16x8*>(A + (size_t)(m0 + r) * K + c * 8);
        if (n0 + r < J) vb = *reinterpret_cast<const f16x8*>(Bt + (size_t)(n0 + r) * K + c * 8);
        *reinterpret_cast<f16x8*>(&As[r * KP + c * 8]) = va;
        *reinterpret_cast<f16x8*>(&Bs[r * KP + c * 8]) = vb;
    }
    __syncthreads();

    int w = tid >> 6, lane = tid & 63;
    int wr = (w >> 2) * 64, wc = (w & 3) * 32;
    int lr = lane & 15, lk = (lane >> 4) * 8;

    f32x4 acc[4][2];
#pragma unroll
    for (int mm = 0; mm < 4; mm++)
#pragma unroll
        for (int nn = 0; nn < 2; nn++) acc[mm][nn] = (f32x4){0.f, 0.f, 0.f, 0.f};

#pragma unroll
    for (int k0 = 0; k0 < K; k0 += 32) {
        f16x8 a[4], b[2];
#pragma unroll
        for (int mm = 0; mm < 4; mm++)
            a[mm] = *reinterpret_cast<const f16x8*>(&As[(wr + mm*16 + lr) * KP + k0 + lk]);
#pragma unroll
        for (int nn = 0; nn < 2; nn++)
            b[nn] = *reinterpret_cast<const f16x8*>(&Bs[(wc + nn*16 + lr) * KP + k0 + lk]);
#pragma unroll
        for (int mm = 0; mm < 4; mm++)
#pragma unroll
            for (int nn = 0; nn < 2; nn++)
                acc[mm][nn] = __builtin_amdgcn_mfma_f32_16x16x32_f16(a[mm], b[nn], acc[mm][nn], 0, 0, 0);
    }

    int g = lane >> 4;
#pragma unroll
    for (int mm = 0; mm < 4; mm++)
#pragma unroll
        for (int nn = 0; nn < 2; nn++) {
            int col = n0 + wc + nn*16 + lr;
            if (col < J) {
#pragma unroll
                for (int q = 0; q < 4; q++) {
                    int row = m0 + wr + mm*16 + g*4 + q;
                    if (row < N) C[(size_t)row * J + col] = (OutT)acc[mm][nn][q];
                }
            }
        }
}

// ---- fused layer-1 aggregation + finalize ----------------------------------
// wave/node; 4 edge-groups x 16 channel-quads; f16x4 loads; ballot counts.
__global__ __launch_bounds__(256)
void k_agg1f(const int* __restrict__ cur, const unsigned* __restrict__ packed,
             const f16* __restrict__ Y1, const float* __restrict__ b1,
             f16* __restrict__ X1h) {
    int n = (blockIdx.x * 256 + threadIdx.x) >> 6;
    if (n >= N_NODES) return;
    int lane = threadIdx.x & 63;
    int deg = cur[n]; if (deg > CAP) deg = CAP;
    unsigned my = packed[(size_t)n * CAP + lane];   // stale for lane>=deg, masked
    int tp = (int)(my % 17u);                       // 0..16 always
    float wreg = 0.f;
#pragma unroll
    for (int r = 0; r < 16; r++) {
        unsigned long long b = __ballot(lane < deg && tp == r);
        if (lane == r) wreg = 1.0f / fmaxf((float)__popcll(b), 1.0f);
    }
    float w_my = __shfl(wreg, tp);                  // my edge's mean weight
    int c4 = lane & 15, grp = lane >> 4;
    const f16* Yb = Y1 + c4 * 4;
    float a0 = 0.f, a1 = 0.f, a2 = 0.f, a3 = 0.f;
    for (int i = 0; i < deg; i += 4) {              // wave-uniform bound
        int idx = i + grp;                          // <= 63 always
        unsigned en = __shfl(my, idx);              // all lanes active
        float we = __shfl(w_my, idx);
        if (idx < deg) {
            f16x4 v = *reinterpret_cast<const f16x4*>(Yb + ((size_t)en << 6));
            a0 += we * (float)v[0]; a1 += we * (float)v[1];
            a2 += we * (float)v[2]; a3 += we * (float)v[3];
        }
    }
    a0 += __shfl_xor(a0, 16); a0 += __shfl_xor(a0, 32);
    a1 += __shfl_xor(a1, 16); a1 += __shfl_xor(a1, 32);
    a2 += __shfl_xor(a2, 16); a2 += __shfl_xor(a2, 32);
    a3 += __shfl_xor(a3, 16); a3 += __shfl_xor(a3, 32);
    if (grp == 0) {
        f16x4 rt = *reinterpret_cast<const f16x4*>(Y1 + ((size_t)n * 17 + 16) * 64 + c4 * 4);
        float4 bb = *reinterpret_cast<const float4*>(b1 + c4 * 4);
        f16x4 o = {(f16)fmaxf(a0 + (float)rt[0] + bb.x, 0.f),
                   (f16)fmaxf(a1 + (float)rt[1] + bb.y, 0.f),
                   (f16)fmaxf(a2 + (float)rt[2] + bb.z, 0.f),
                   (f16)fmaxf(a3 + (float)rt[3] + bb.w, 0.f)};
        *reinterpret_cast<f16x4*>(X1h + (size_t)n * HID + c4 * 4) = o;
    }
}

// ---- fused layer-2 aggregation + finalize ----------------------------------
// wave/node; 16 edge-groups x 4 channel-quads; float4 loads (Y2 f32).
__global__ __launch_bounds__(256)
void k_agg2f(const int* __restrict__ cur, const unsigned* __restrict__ packed,
             const float* __restrict__ Y2, const float* __restrict__ b2,
             float* __restrict__ out) {
    int n = (blockIdx.x * 256 + threadIdx.x) >> 6;
    if (n >= N_NODES) return;
    int lane = threadIdx.x & 63;
    int deg = cur[n]; if (deg > CAP) deg = CAP;
    unsigned my = packed[(size_t)n * CAP + lane];
    int tp = (int)(my % 17u);
    float wreg = 0.f;
#pragma unroll
    for (int r = 0; r < 16; r++) {
        unsigned long long b = __ballot(lane < deg && tp == r);
        if (lane == r) wreg = 1.0f / fmaxf((float)__popcll(b), 1.0f);
    }
    float w_my = __shfl(wreg, tp);
    int c4 = lane & 3, grp = lane >> 2;             // 16 groups x 4 quads
    const float* Yb = Y2 + c4 * 4;
    float a0 = 0.f, a1 = 0.f, a2 = 0.f, a3 = 0.f;
    for (int i = 0; i < deg; i += 16) {             // usually 1-2 iterations
        int idx = i + grp;                          // <= 63 always (i<=48,grp<=15)
        unsigned en = __shfl(my, idx);
        float we = __shfl(w_my, idx);
        if (idx < deg) {
            float4 v = *reinterpret_cast<const float4*>(Yb + ((size_t)en << 4));
            a0 += we * v.x; a1 += we * v.y; a2 += we * v.z; a3 += we * v.w;
        }
    }
#pragma unroll
    for (int sh = 4; sh <= 32; sh <<= 1) {
        a0 += __shfl_xor(a0, sh); a1 += __shfl_xor(a1, sh);
        a2 += __shfl_xor(a2, sh); a3 += __shfl_xor(a3, sh);
    }
    if (grp == 0) {                                 // lanes 0..3
        float4 rt = *reinterpret_cast<const float4*>(Y2 + ((size_t)n * 17 + 16) * 16 + c4 * 4);
        float4 bb = *reinterpret_cast<const float4*>(b2 + c4 * 4);
        float4 o;
        o.x = 1.0f / (1.0f + expf(-(a0 + rt.x + bb.x)));
        o.y = 1.0f / (1.0f + expf(-(a1 + rt.y + bb.y)));
        o.z = 1.0f / (1.0f + expf(-(a2 + rt.z + bb.z)));
        o.w = 1.0f / (1.0f + expf(-(a3 + rt.w + bb.w)));
        *reinterpret_cast<float4*>(out + (size_t)n * NC + c4 * 4) = o;
    }
}

extern "C" void kernel_launch(void* const* d_in, const int* in_sizes, int n_in,
                              void* d_out, int out_size, void* d_ws, size_t ws_size,
                              hipStream_t stream) {
    const float* emb   = (const float*)d_in[0];
    const float* W1    = (const float*)d_in[1];
    const float* root1 = (const float*)d_in[2];
    const float* b1    = (const float*)d_in[3];
    const float* W2    = (const float*)d_in[4];
    const float* root2 = (const float*)d_in[5];
    const float* b2    = (const float*)d_in[6];
    const int*   ei    = (const int*)d_in[7];    // [2, NE]: src then dst
    const int*   et    = (const int*)d_in[8];
    float* out = (float*)d_out;

    char* ws = (char*)d_ws;
    // ws layout (bytes), total 134,913,344:
    //   cur:      0          .. +200,000      (50000 i32)
    //   Bt1:      200,000    .. +278,528      (1088x128 f16)
    //   Bt2:      478,528    .. +34,816       (272x64 f16)
    //   packed:   513,344    .. +12,800,000   (50000x64 u32 buckets)
    //   embh/X1h: 13,313,344 .. +12,800,000   (embh dies at gemm1; X1h aliases)
    //   Y1/Y2:    26,113,344 .. +108,800,000  (Y1 f16 [50000][1088]; Y2 f32 [50000][272])
    int*      cur    = (int*)(ws + 0);
    f16*      Bt1    = (f16*)(ws + 200000);
    f16*      Bt2    = (f16*)(ws + 478528);
    unsigned* packed = (unsigned*)(ws + 513344);
    f16*      embh   = (f16*)(ws + 13313344);
    f16*      X1h    = (f16*)(ws + 13313344);    // aliases embh (disjoint lifetime)
    f16*      Y1     = (f16*)(ws + 26113344);
    float*    Y2     = (float*)(ws + 26113344);  // aliases Y1 (dead after agg1f)

    // pre: cast(6250) + build_B(613) + cur-zero(196) = 7059 blocks
    k_pre<<<7059, 256, 0, stream>>>(emb, W1, root1, W2, root2, embh, Bt1, Bt2, cur);

    // hybrid gemm1+scatter: 391 groups x 13 = 5083 blocks (9 gemm + 4 scatter each)
    k_g1s<<<391 * 13, 512, 0, stream>>>(embh, Bt1, Y1, ei, et, cur, packed);

    k_agg1f<<<(N_NODES * 64 + 255) / 256, 256, 0, stream>>>(cur, packed, Y1, b1, X1h);

    dim3 g2((J2 + 127) / 128, (N_NODES + 127) / 128);   // 3 x 391
    k_mfma<HID, float><<<g2, 512, 0, stream>>>(X1h, Bt2, Y2, N_NODES, J2);

    k_agg2f<<<(N_NODES * 64 + 255) / 256, 256, 0, stream>>>(cur, packed, Y2, b2, out);
}